// Round 20
// baseline (368.028 us; speedup 1.0000x reference)
//
#include <hip/hip_runtime.h>
#include <cstdint>
#include <cstddef>

typedef unsigned short ushort_t;
typedef __attribute__((ext_vector_type(8))) short short8;   // 8 bf16 (4 VGPRs)
typedef __attribute__((ext_vector_type(4))) float f32x4;    // MFMA acc

// Problem constants (from reference)
constexpr int N_NODES = 100000;
constexpr int N_EDGES = 1000000;

#if __has_builtin(__builtin_amdgcn_exp2f)
#define EXP2(x) __builtin_amdgcn_exp2f(x)
#else
#define EXP2(x) exp2f(x)
#endif

// ---- bf16 pack/unpack (RNE) ----
__device__ __forceinline__ unsigned bf16rne(float f) {
    unsigned u = __float_as_uint(f);
    return (u + 0x7FFFu + ((u >> 16) & 1u)) >> 16;
}
__device__ __forceinline__ unsigned pack2(float lo, float hi) {
    return bf16rne(lo) | (bf16rne(hi) << 16);
}
__device__ __forceinline__ float unpack_lo(unsigned u) { return __uint_as_float(u << 16); }
__device__ __forceinline__ float unpack_hi(unsigned u) { return __uint_as_float(u & 0xFFFF0000u); }
__device__ __forceinline__ float bf2f(ushort_t u) { return __uint_as_float(((unsigned)u) << 16); }

// ---- DPP butterfly add (ctrl is a template constant) ----
template<int CTRL>
__device__ __forceinline__ float dpp_add(float x) {
    int v = __builtin_amdgcn_update_dpp(0, __float_as_int(x), CTRL, 0xF, 0xF, true);
    return x + __int_as_float(v);
}
// all-reduce within each 32-lane group
__device__ __forceinline__ float reduce32(float p) {
    p = dpp_add<0xB1>(p);    // quad_perm [1,0,3,2]
    p = dpp_add<0x4E>(p);    // quad_perm [2,3,0,1]
    p = dpp_add<0x141>(p);   // row_half_mirror
    p = dpp_add<0x140>(p);   // row_mirror
    p += __int_as_float(__builtin_amdgcn_ds_swizzle(__float_as_int(p), 0x401F));
    return p;
}

// ============================ CSR build ============================
__global__ void hist_kernel(const int* __restrict__ dst, int* __restrict__ cnt) {
    int i = blockIdx.x * blockDim.x + threadIdx.x;
    if (i < N_EDGES) atomicAdd(&cnt[dst[i]], 1);
}

__global__ __launch_bounds__(256) void scan1(const int* __restrict__ cnt,
    int* __restrict__ excl, int* __restrict__ bsum, int n) {
    __shared__ int sh[256];
    int b = blockIdx.x, t = threadIdx.x;
    int base = b * 1024 + t * 4;
    int v0 = (base + 0 < n) ? cnt[base + 0] : 0;
    int v1 = (base + 1 < n) ? cnt[base + 1] : 0;
    int v2 = (base + 2 < n) ? cnt[base + 2] : 0;
    int v3 = (base + 3 < n) ? cnt[base + 3] : 0;
    int s = v0 + v1 + v2 + v3;
    sh[t] = s;
    __syncthreads();
    for (int off = 1; off < 256; off <<= 1) {
        int val = (t >= off) ? sh[t - off] : 0;
        __syncthreads();
        sh[t] += val;
        __syncthreads();
    }
    int prefix = sh[t] - s;
    if (t == 255) bsum[b] = sh[255];
    if (base + 0 < n) excl[base + 0] = prefix;
    if (base + 1 < n) excl[base + 1] = prefix + v0;
    if (base + 2 < n) excl[base + 2] = prefix + v0 + v1;
    if (base + 3 < n) excl[base + 3] = prefix + v0 + v1 + v2;
}

__global__ __launch_bounds__(128) void scan2(int* __restrict__ bsum, int nb) {
    __shared__ int sh[128];
    int t = threadIdx.x;
    int v = (t < nb) ? bsum[t] : 0;
    sh[t] = v;
    __syncthreads();
    for (int off = 1; off < 128; off <<= 1) {
        int val = (t >= off) ? sh[t - off] : 0;
        __syncthreads();
        sh[t] += val;
        __syncthreads();
    }
    if (t < nb) bsum[t] = sh[t] - v;
}

__global__ void scan3(const int* __restrict__ excl, const int* __restrict__ bsum,
                      int* __restrict__ rowptr, int* __restrict__ cursor, int n) {
    int i = blockIdx.x * blockDim.x + threadIdx.x;
    if (i < n) { int r = excl[i] + bsum[i >> 10]; rowptr[i] = r; cursor[i] = r; }
    if (i == n) rowptr[n] = N_EDGES;
}

// scatter (edge id, src node) as one int2 into dst-sorted order.
__global__ void scatter_kernel(const int* __restrict__ dst, const int* __restrict__ src,
                               int* __restrict__ cursor, int2* __restrict__ es) {
    int e = blockIdx.x * blockDim.x + threadIdx.x;
    if (e < N_EDGES) {
        int p = atomicAdd(&cursor[dst[e]], 1);
        es[p] = make_int2(e, src[e]);
    }
}

// ============================ weight prep (Wg inline) ============================
__device__ __forceinline__ const float* sel4(int m, const float* q, const float* k,
                                             const float* v, const float* s) {
    switch (m) { case 0: return q; case 2: return k; case 3: return v; default: return s; }
}

__global__ __launch_bounds__(256) void prep_weights(
    const float* Wq1, const float* Wk1, const float* Wv1, const float* Ws1,
    const float* bq1, const float* bk1, const float* bv1, const float* bs1, const float* We1,
    const float* Wq2, const float* Wk2, const float* Wv2, const float* Ws2,
    const float* bq2, const float* bk2, const float* bv2, const float* bs2, const float* We2,
    ushort_t* Wtb1, float* bcat1, ushort_t* Wtb2, float* bcat2, int* cnt)
{
    const int T1 = 320 * 128, T2 = 320 * 64;
    int stride = gridDim.x * blockDim.x;
    for (int i = blockIdx.x * blockDim.x + threadIdx.x;
         i < T1 + T2 + 640 + N_NODES; i += stride) {
        if (i < T1) {
            int col = i / 128, kk = i % 128;
            int m = col >> 6, c = col & 63;
            float v;
            if (m == 1) {                    // g = Wq (.) We, per head
                int h = c >> 5, j = c & 31;
                float s = 0.f;
                #pragma unroll 8
                for (int cc = 0; cc < 32; ++cc)
                    s = fmaf(Wq1[kk * 64 + h * 32 + cc], We1[j * 64 + h * 32 + cc], s);
                v = s;
            } else {
                v = sel4(m, Wq1, Wk1, Wv1, Ws1)[kk * 64 + c];
            }
            Wtb1[i] = (ushort_t)bf16rne(v);
        } else if (i < T1 + T2) {
            int jj = i - T1;
            int col = jj / 64, kk = jj % 64;
            int m = col >> 6, c = col & 63;
            float v;
            if (m == 1) {
                if (c < 32) {
                    float s = 0.f;
                    #pragma unroll 8
                    for (int cc = 0; cc < 64; ++cc)
                        s = fmaf(Wq2[kk * 64 + cc], We2[c * 64 + cc], s);
                    v = s;
                } else v = 0.f;
            } else {
                v = sel4(m, Wq2, Wk2, Wv2, Ws2)[kk * 64 + c];
            }
            Wtb2[jj] = (ushort_t)bf16rne(v);
        } else if (i < T1 + T2 + 640) {
            int j = i - T1 - T2;
            if (j < 320) {
                int m = j >> 6, c = j & 63;
                float v;
                if (m == 1) {
                    int h = c >> 5, jjj = c & 31;
                    float s = 0.f;
                    for (int cc = 0; cc < 32; ++cc)
                        s = fmaf(bq1[h * 32 + cc], We1[jjj * 64 + h * 32 + cc], s);
                    v = s;
                } else v = sel4(m, bq1, bk1, bv1, bs1)[c];
                bcat1[j] = v;
            } else {
                int jl = j - 320;
                int m = jl >> 6, c = jl & 63;
                float v;
                if (m == 1) {
                    if (c < 32) {
                        float s = 0.f;
                        for (int cc = 0; cc < 64; ++cc)
                            s = fmaf(bq2[cc], We2[c * 64 + cc], s);
                        v = s;
                    } else v = 0.f;
                } else v = sel4(m, bq2, bk2, bv2, bs2)[c];
                bcat2[jl] = v;
            }
        } else {
            cnt[i - (T1 + T2 + 640)] = 0;
        }
    }
}

// ============================ MFMA node GEMM (r11 proven, skp bf16) ============================
template<int K, typename TIN>
__global__ __launch_bounds__(256) void gemm_mfma(
    const TIN* __restrict__ xin,          // [N][K]
    const ushort_t* __restrict__ Wtb,     // [320][K] bf16
    const float* __restrict__ bcat,       // [320]
    unsigned* __restrict__ qgp,           // [N][64] pack(q,g)
    unsigned* __restrict__ kvp,           // [N][64] pack(k,v)
    ushort_t* __restrict__ skp)           // [N][64] bf16 skip
{
    constexpr int KP = K + 8;
    __shared__ ushort_t As[32][KP];

    int t = threadIdx.x;
    int lane = t & 63, w = t >> 6;
    int m0 = blockIdx.x * 32;
    int cl = lane & 15;
    int q4 = lane >> 4;
    int col = w * 16 + cl;

    short8 bfrag[5][K / 32];
    #pragma unroll
    for (int m = 0; m < 5; ++m)
        #pragma unroll
        for (int ks = 0; ks < K / 32; ++ks)
            bfrag[m][ks] = *(const short8*)&Wtb[(size_t)(m * 64 + col) * K + ks * 32 + q4 * 8];
    float bias[5];
    #pragma unroll
    for (int m = 0; m < 5; ++m) bias[m] = bcat[m * 64 + col];

    if constexpr (sizeof(TIN) == 4) {
        constexpr int C4 = K / 4;
        #pragma unroll
        for (int it = 0; it < 32 * C4 / 256; ++it) {
            int idx = it * 256 + t;
            int row = idx / C4, c4 = idx % C4;
            float4 xv = *(const float4*)&((const float*)xin)[(size_t)(m0 + row) * K + c4 * 4];
            *(uint2*)&As[row][c4 * 4] = make_uint2(pack2(xv.x, xv.y), pack2(xv.z, xv.w));
        }
    } else {
        constexpr int C4 = K / 4;
        #pragma unroll
        for (int it = 0; it < 32 * C4 / 256; ++it) {
            int idx = it * 256 + t;
            int row = idx / C4, c4 = idx % C4;
            uint2 u = *(const uint2*)&((const ushort_t*)xin)[(size_t)(m0 + row) * K + c4 * 4];
            *(uint2*)&As[row][c4 * 4] = u;
        }
    }
    __syncthreads();

    f32x4 acc[5][2];
    f32x4 zero = {0.f, 0.f, 0.f, 0.f};
    #pragma unroll
    for (int m = 0; m < 5; ++m) { acc[m][0] = zero; acc[m][1] = zero; }

    #pragma unroll
    for (int ks = 0; ks < K / 32; ++ks) {
        short8 a0 = *(const short8*)&As[cl][ks * 32 + q4 * 8];
        short8 a1 = *(const short8*)&As[16 + cl][ks * 32 + q4 * 8];
        #pragma unroll
        for (int m = 0; m < 5; ++m) {
            acc[m][0] = __builtin_amdgcn_mfma_f32_16x16x32_bf16(a0, bfrag[m][ks], acc[m][0], 0, 0, 0);
            acc[m][1] = __builtin_amdgcn_mfma_f32_16x16x32_bf16(a1, bfrag[m][ks], acc[m][1], 0, 0, 0);
        }
    }

    #pragma unroll
    for (int rt = 0; rt < 2; ++rt) {
        #pragma unroll
        for (int r = 0; r < 4; ++r) {
            int row = m0 + rt * 16 + q4 * 4 + r;
            float qv = acc[0][rt][r] + bias[0];
            float gv = acc[1][rt][r] + bias[1];
            float kk = acc[2][rt][r] + bias[2];
            float vv = acc[3][rt][r] + bias[3];
            float sv = acc[4][rt][r] + bias[4];
            qgp[(size_t)row * 64 + col] = pack2(qv, gv);
            kvp[(size_t)row * 64 + col] = pack2(kk, vv);
            skp[(size_t)row * 64 + col] = (ushort_t)bf16rne(sv);
        }
    }
}

// ============================ CSR edge pass v13 ============================
// r19 structure with depth-3 software pipeline: 6 named slots (3 iterations of
// 2 edges in flight, 12 outstanding loads). Slot rotation is register renaming
// under unroll. Clampless (lanes>=rem hold 0 -> safe row-0 dummy loads).
template<int C, int CHUNK, typename OT>
__global__ __launch_bounds__(256) void edge_csr(
    const int* __restrict__ rowptr, const int2* __restrict__ es,
    const float* __restrict__ ef, const float* __restrict__ We,
    const unsigned* __restrict__ qgp, const unsigned* __restrict__ kvp,
    const ushort_t* __restrict__ skp, OT* __restrict__ out,
    float scale, int do_relu)
{
    __shared__ float Wel[32 * 64];
    __shared__ float exl[4][64];
    int t = threadIdx.x;
    for (int i = t; i < 32 * 64; i += 256) Wel[i] = We[i];
    __syncthreads();

    int lane  = t & 63;
    int wslot = t >> 6;
    int col   = lane & 31;
    int hsel  = (C == 64) ? 0 : (lane >> 5);

    int wid = blockIdx.x * 4 + wslot;
    int nw  = gridDim.x * 4;

    for (int d0 = wid; d0 < N_NODES; d0 += nw) {
        int d = __builtin_amdgcn_readfirstlane(d0);
        int r0 = rowptr[d], r1 = rowptr[d + 1];
        unsigned uqg = __builtin_nontemporal_load(&qgp[(size_t)d * 64 + lane]);
        float qv = unpack_lo(uqg), gv = unpack_hi(uqg);
        float racc = 0.f, efacc = 0.f, rden = 0.f;

        for (int c0 = r0; c0 < r1; c0 += CHUNK) {
            int rem = min(CHUNK, r1 - c0);
            long long ll = (lane < rem)
                ? __builtin_nontemporal_load((const long long*)&es[c0 + lane]) : 0LL;
            int e_l = (int)ll;
            int s_l = (int)(ll >> 32);

            // prologue: edges 0..5 into slots S0..S5 (indices >= rem read 0 -> row 0)
            float ef0, ef1, ef2, ef3, ef4, ef5;
            unsigned u0, u1, u2, u3, u4, u5;
            #define LOADSLOT(EFV, UV, IDX)                                          \
                {                                                                   \
                    int e_ = __builtin_amdgcn_readlane(e_l, (IDX));                 \
                    int s_ = __builtin_amdgcn_readlane(s_l, (IDX));                 \
                    EFV = __builtin_nontemporal_load(&ef[(size_t)e_ * 32 + col]);   \
                    UV  = kvp[(size_t)s_ * 64 + lane];                              \
                }
            LOADSLOT(ef0, u0, 0) LOADSLOT(ef1, u1, 1)
            LOADSLOT(ef2, u2, 2) LOADSLOT(ef3, u3, 3)
            LOADSLOT(ef4, u4, 4) LOADSLOT(ef5, u5, 5)

            #pragma unroll 3
            for (int i = 0; i < rem; i += 2) {
                // refill two slots for edges i+6, i+7 (issued before consume)
                float efN0, efN1; unsigned uN0, uN1;
                LOADSLOT(efN0, uN0, i + 6)
                LOADSLOT(efN1, uN1, i + 7)

                // consume S0 (edge i -- always valid)
                {
                    float kk = unpack_lo(u0), vv = unpack_hi(u0);
                    float p = reduce32(fmaf(qv, kk, ef0 * gv));
                    if (C == 64) p += __shfl_xor(p, 32, 64);
                    float ex = EXP2(p * scale);
                    racc  = fmaf(vv,  ex, racc);
                    efacc = fmaf(ef0, ex, efacc);
                    rden += ex;
                }
                // consume S1 (edge i+1)
                if (i + 1 < rem) {
                    float kk = unpack_lo(u1), vv = unpack_hi(u1);
                    float p = reduce32(fmaf(qv, kk, ef1 * gv));
                    if (C == 64) p += __shfl_xor(p, 32, 64);
                    float ex = EXP2(p * scale);
                    racc  = fmaf(vv,  ex, racc);
                    efacc = fmaf(ef1, ex, efacc);
                    rden += ex;
                }

                // rotate slots by 2
                ef0 = ef2; u0 = u2;  ef1 = ef3; u1 = u3;
                ef2 = ef4; u2 = u4;  ef3 = ef5; u3 = u5;
                ef4 = efN0; u4 = uN0; ef5 = efN1; u5 = uN1;
            }
            #undef LOADSLOT
        }

        // finalize: (racc + efacc @ We) / rden + skip
        exl[wslot][lane] = efacc;
        float mv = 0.f;
        #pragma unroll 8
        for (int j = 0; j < 32; ++j)
            mv = fmaf(exl[wslot][hsel * 32 + j], Wel[j * 64 + lane], mv);
        float val = (racc + mv) / (rden + 1e-16f)
                  + bf2f(__builtin_nontemporal_load(&skp[(size_t)d * 64 + lane]));
        if (do_relu) val = fmaxf(val, 0.f);
        if constexpr (sizeof(OT) == 4)
            __builtin_nontemporal_store(val, &out[(size_t)d * 64 + lane]);
        else
            out[(size_t)d * 64 + lane] = (OT)bf16rne(val);
    }
}

extern "C" void kernel_launch(void* const* d_in, const int* in_sizes, int n_in,
                              void* d_out, int out_size, void* d_ws, size_t ws_size,
                              hipStream_t stream) {
    const float* x   = (const float*)d_in[0];
    const int*   ei  = (const int*)d_in[1];
    const float* ef  = (const float*)d_in[2];
    const float* Wq1 = (const float*)d_in[3];  const float* bq1 = (const float*)d_in[4];
    const float* Wk1 = (const float*)d_in[5];  const float* bk1 = (const float*)d_in[6];
    const float* Wv1 = (const float*)d_in[7];  const float* bv1 = (const float*)d_in[8];
    const float* We1 = (const float*)d_in[9];
    const float* Ws1 = (const float*)d_in[10]; const float* bs1 = (const float*)d_in[11];
    const float* Wq2 = (const float*)d_in[12]; const float* bq2 = (const float*)d_in[13];
    const float* Wk2 = (const float*)d_in[14]; const float* bk2 = (const float*)d_in[15];
    const float* Wv2 = (const float*)d_in[16]; const float* bv2 = (const float*)d_in[17];
    const float* We2 = (const float*)d_in[18];
    const float* Ws2 = (const float*)d_in[19]; const float* bs2 = (const float*)d_in[20];
    float* out = (float*)d_out;

    const int N = N_NODES, E = N_EDGES;
    size_t NF = (size_t)N * 64;
    unsigned* qgp  = (unsigned*)d_ws;              // N*64 u32 (bf16 q|g)
    unsigned* kvp  = qgp + NF;                     // N*64 u32 (bf16 k|v)
    ushort_t* skp  = (ushort_t*)(kvp + NF);        // N*64 bf16 skip
    ushort_t* h1b  = skp + NF;                     // N*64 bf16 (layer-1 output)
    ushort_t* Wtb1 = h1b + NF;                     // 320*128 bf16
    float*    bcat1= (float*)(Wtb1 + 320 * 128);   // 320
    ushort_t* Wtb2 = (ushort_t*)(bcat1 + 320);     // 320*64 bf16
    float*    bcat2= (float*)(Wtb2 + 320 * 64);    // 320
    int* cnt    = (int*)(bcat2 + 320);             // N
    int* excl   = cnt + N;                         // N
    int* bsum   = excl + N;                        // 128
    int* cursor = bsum + 128;                      // N
    int* rowptr = cursor + N;                      // N+1 (+1 pad)
    int2* es    = (int2*)(rowptr + N + 2);         // E (edge id | src), 8B aligned

    const int* src = ei;
    const int* dst = ei + E;

    dim3 b256(256);
    int gN1   = (N + 1 + 255) / 256;
    int gE    = (E + 255) / 256;
    int gGemm = N / 32;                            // 3125 exactly
    int gEdge = 2048;
    int nScanB = (N + 1023) / 1024;

    // scale premultiplied by log2(e) for exp2
    const float s1 = 0.17677669529663687f * 1.4426950408889634f;
    const float s2 = 0.125f * 1.4426950408889634f;

    // ---------------- weight prep + cnt zeroing (one launch) ----------------
    hipLaunchKernelGGL(prep_weights, dim3(96), b256, 0, stream,
                       Wq1, Wk1, Wv1, Ws1, bq1, bk1, bv1, bs1, We1,
                       Wq2, Wk2, Wv2, Ws2, bq2, bk2, bv2, bs2, We2,
                       Wtb1, bcat1, Wtb2, bcat2, cnt);

    // ---------------- CSR build (shared by both layers) ----------------
    hipLaunchKernelGGL(hist_kernel, dim3(gE), b256, 0, stream, dst, cnt);
    hipLaunchKernelGGL(scan1, dim3(nScanB), b256, 0, stream, cnt, excl, bsum, N);
    hipLaunchKernelGGL(scan2, dim3(1), dim3(128), 0, stream, bsum, nScanB);
    hipLaunchKernelGGL(scan3, dim3(gN1), b256, 0, stream, excl, bsum, rowptr, cursor, N);
    hipLaunchKernelGGL(scatter_kernel, dim3(gE), b256, 0, stream, dst, src, cursor, es);

    // ---------------- layer 1: H=2, C=32, K=128 ----------------
    hipLaunchKernelGGL((gemm_mfma<128, float>), dim3(gGemm), b256, 0, stream,
                       x, Wtb1, bcat1, qgp, kvp, skp);
    hipLaunchKernelGGL((edge_csr<32, 16, ushort_t>), dim3(gEdge), b256, 0, stream,
                       rowptr, es, ef, We1, qgp, kvp, skp, h1b, s1, 1);

    // ---------------- layer 2: H=1, C=64, K=64 ----------------
    hipLaunchKernelGGL((gemm_mfma<64, ushort_t>), dim3(gGemm), b256, 0, stream,
                       h1b, Wtb2, bcat2, qgp, kvp, skp);
    hipLaunchKernelGGL((edge_csr<64, 16, float>), dim3(gEdge), b256, 0, stream,
                       rowptr, es, ef, We2, qgp, kvp, skp, out, s2, 0);
}

// Round 21
// 360.027 us; speedup vs baseline: 1.0222x; 1.0222x over previous
//
#include <hip/hip_runtime.h>
#include <cstdint>
#include <cstddef>

typedef unsigned short ushort_t;
typedef __attribute__((ext_vector_type(8))) short short8;   // 8 bf16 (4 VGPRs)
typedef __attribute__((ext_vector_type(4))) float f32x4;    // MFMA acc

// Problem constants (from reference)
constexpr int N_NODES = 100000;
constexpr int N_EDGES = 1000000;

#if __has_builtin(__builtin_amdgcn_exp2f)
#define EXP2(x) __builtin_amdgcn_exp2f(x)
#else
#define EXP2(x) exp2f(x)
#endif

// ---- bf16 pack/unpack (RNE) ----
__device__ __forceinline__ unsigned bf16rne(float f) {
    unsigned u = __float_as_uint(f);
    return (u + 0x7FFFu + ((u >> 16) & 1u)) >> 16;
}
__device__ __forceinline__ unsigned pack2(float lo, float hi) {
    return bf16rne(lo) | (bf16rne(hi) << 16);
}
__device__ __forceinline__ float unpack_lo(unsigned u) { return __uint_as_float(u << 16); }
__device__ __forceinline__ float unpack_hi(unsigned u) { return __uint_as_float(u & 0xFFFF0000u); }
__device__ __forceinline__ float bf2f(ushort_t u) { return __uint_as_float(((unsigned)u) << 16); }

// ---- DPP butterfly add (ctrl is a template constant) ----
template<int CTRL>
__device__ __forceinline__ float dpp_add(float x) {
    int v = __builtin_amdgcn_update_dpp(0, __float_as_int(x), CTRL, 0xF, 0xF, true);
    return x + __int_as_float(v);
}
// all-reduce within each 32-lane group
__device__ __forceinline__ float reduce32(float p) {
    p = dpp_add<0xB1>(p);    // quad_perm [1,0,3,2]
    p = dpp_add<0x4E>(p);    // quad_perm [2,3,0,1]
    p = dpp_add<0x141>(p);   // row_half_mirror
    p = dpp_add<0x140>(p);   // row_mirror
    p += __int_as_float(__builtin_amdgcn_ds_swizzle(__float_as_int(p), 0x401F));
    return p;
}

// ============================ CSR build ============================
__global__ void hist_kernel(const int* __restrict__ dst, int* __restrict__ cnt) {
    int i = blockIdx.x * blockDim.x + threadIdx.x;
    if (i < N_EDGES) atomicAdd(&cnt[dst[i]], 1);
}

__global__ __launch_bounds__(256) void scan1(const int* __restrict__ cnt,
    int* __restrict__ excl, int* __restrict__ bsum, int n) {
    __shared__ int sh[256];
    int b = blockIdx.x, t = threadIdx.x;
    int base = b * 1024 + t * 4;
    int v0 = (base + 0 < n) ? cnt[base + 0] : 0;
    int v1 = (base + 1 < n) ? cnt[base + 1] : 0;
    int v2 = (base + 2 < n) ? cnt[base + 2] : 0;
    int v3 = (base + 3 < n) ? cnt[base + 3] : 0;
    int s = v0 + v1 + v2 + v3;
    sh[t] = s;
    __syncthreads();
    for (int off = 1; off < 256; off <<= 1) {
        int val = (t >= off) ? sh[t - off] : 0;
        __syncthreads();
        sh[t] += val;
        __syncthreads();
    }
    int prefix = sh[t] - s;
    if (t == 255) bsum[b] = sh[255];
    if (base + 0 < n) excl[base + 0] = prefix;
    if (base + 1 < n) excl[base + 1] = prefix + v0;
    if (base + 2 < n) excl[base + 2] = prefix + v0 + v1;
    if (base + 3 < n) excl[base + 3] = prefix + v0 + v1 + v2;
}

__global__ __launch_bounds__(128) void scan2(int* __restrict__ bsum, int nb) {
    __shared__ int sh[128];
    int t = threadIdx.x;
    int v = (t < nb) ? bsum[t] : 0;
    sh[t] = v;
    __syncthreads();
    for (int off = 1; off < 128; off <<= 1) {
        int val = (t >= off) ? sh[t - off] : 0;
        __syncthreads();
        sh[t] += val;
        __syncthreads();
    }
    if (t < nb) bsum[t] = sh[t] - v;
}

__global__ void scan3(const int* __restrict__ excl, const int* __restrict__ bsum,
                      int* __restrict__ rowptr, int* __restrict__ cursor, int n) {
    int i = blockIdx.x * blockDim.x + threadIdx.x;
    if (i < n) { int r = excl[i] + bsum[i >> 10]; rowptr[i] = r; cursor[i] = r; }
    if (i == n) rowptr[n] = N_EDGES;
}

// scatter (edge id, src node) as one int2 into dst-sorted order.
// 8B random writes into an 8MB array -> L2-absorbed.
__global__ void scatter_kernel(const int* __restrict__ dst, const int* __restrict__ src,
                               int* __restrict__ cursor, int2* __restrict__ es) {
    int e = blockIdx.x * blockDim.x + threadIdx.x;
    if (e < N_EDGES) {
        int p = atomicAdd(&cursor[dst[e]], 1);
        es[p] = make_int2(e, src[e]);
    }
}

// ============================ weight prep (Wg inline) ============================
__device__ __forceinline__ const float* sel4(int m, const float* q, const float* k,
                                             const float* v, const float* s) {
    switch (m) { case 0: return q; case 2: return k; case 3: return v; default: return s; }
}

__global__ __launch_bounds__(256) void prep_weights(
    const float* Wq1, const float* Wk1, const float* Wv1, const float* Ws1,
    const float* bq1, const float* bk1, const float* bv1, const float* bs1, const float* We1,
    const float* Wq2, const float* Wk2, const float* Wv2, const float* Ws2,
    const float* bq2, const float* bk2, const float* bv2, const float* bs2, const float* We2,
    ushort_t* Wtb1, float* bcat1, ushort_t* Wtb2, float* bcat2, int* cnt)
{
    const int T1 = 320 * 128, T2 = 320 * 64;
    int stride = gridDim.x * blockDim.x;
    for (int i = blockIdx.x * blockDim.x + threadIdx.x;
         i < T1 + T2 + 640 + N_NODES; i += stride) {
        if (i < T1) {
            int col = i / 128, kk = i % 128;
            int m = col >> 6, c = col & 63;
            float v;
            if (m == 1) {                    // g = Wq (.) We, per head
                int h = c >> 5, j = c & 31;
                float s = 0.f;
                #pragma unroll 8
                for (int cc = 0; cc < 32; ++cc)
                    s = fmaf(Wq1[kk * 64 + h * 32 + cc], We1[j * 64 + h * 32 + cc], s);
                v = s;
            } else {
                v = sel4(m, Wq1, Wk1, Wv1, Ws1)[kk * 64 + c];
            }
            Wtb1[i] = (ushort_t)bf16rne(v);
        } else if (i < T1 + T2) {
            int jj = i - T1;
            int col = jj / 64, kk = jj % 64;
            int m = col >> 6, c = col & 63;
            float v;
            if (m == 1) {
                if (c < 32) {
                    float s = 0.f;
                    #pragma unroll 8
                    for (int cc = 0; cc < 64; ++cc)
                        s = fmaf(Wq2[kk * 64 + cc], We2[c * 64 + cc], s);
                    v = s;
                } else v = 0.f;
            } else {
                v = sel4(m, Wq2, Wk2, Wv2, Ws2)[kk * 64 + c];
            }
            Wtb2[jj] = (ushort_t)bf16rne(v);
        } else if (i < T1 + T2 + 640) {
            int j = i - T1 - T2;
            if (j < 320) {
                int m = j >> 6, c = j & 63;
                float v;
                if (m == 1) {
                    int h = c >> 5, jjj = c & 31;
                    float s = 0.f;
                    for (int cc = 0; cc < 32; ++cc)
                        s = fmaf(bq1[h * 32 + cc], We1[jjj * 64 + h * 32 + cc], s);
                    v = s;
                } else v = sel4(m, bq1, bk1, bv1, bs1)[c];
                bcat1[j] = v;
            } else {
                int jl = j - 320;
                int m = jl >> 6, c = jl & 63;
                float v;
                if (m == 1) {
                    if (c < 32) {
                        float s = 0.f;
                        for (int cc = 0; cc < 64; ++cc)
                            s = fmaf(bq2[cc], We2[c * 64 + cc], s);
                        v = s;
                    } else v = 0.f;
                } else v = sel4(m, bq2, bk2, bv2, bs2)[c];
                bcat2[jl] = v;
            }
        } else {
            cnt[i - (T1 + T2 + 640)] = 0;
        }
    }
}

// ============================ MFMA node GEMM (r11 proven, skp bf16) ============================
template<int K, typename TIN>
__global__ __launch_bounds__(256) void gemm_mfma(
    const TIN* __restrict__ xin,          // [N][K]
    const ushort_t* __restrict__ Wtb,     // [320][K] bf16
    const float* __restrict__ bcat,       // [320]
    unsigned* __restrict__ qgp,           // [N][64] pack(q,g)
    unsigned* __restrict__ kvp,           // [N][64] pack(k,v)
    ushort_t* __restrict__ skp)           // [N][64] bf16 skip
{
    constexpr int KP = K + 8;
    __shared__ ushort_t As[32][KP];

    int t = threadIdx.x;
    int lane = t & 63, w = t >> 6;
    int m0 = blockIdx.x * 32;
    int cl = lane & 15;
    int q4 = lane >> 4;
    int col = w * 16 + cl;

    short8 bfrag[5][K / 32];
    #pragma unroll
    for (int m = 0; m < 5; ++m)
        #pragma unroll
        for (int ks = 0; ks < K / 32; ++ks)
            bfrag[m][ks] = *(const short8*)&Wtb[(size_t)(m * 64 + col) * K + ks * 32 + q4 * 8];
    float bias[5];
    #pragma unroll
    for (int m = 0; m < 5; ++m) bias[m] = bcat[m * 64 + col];

    if constexpr (sizeof(TIN) == 4) {
        constexpr int C4 = K / 4;
        #pragma unroll
        for (int it = 0; it < 32 * C4 / 256; ++it) {
            int idx = it * 256 + t;
            int row = idx / C4, c4 = idx % C4;
            float4 xv = *(const float4*)&((const float*)xin)[(size_t)(m0 + row) * K + c4 * 4];
            *(uint2*)&As[row][c4 * 4] = make_uint2(pack2(xv.x, xv.y), pack2(xv.z, xv.w));
        }
    } else {
        constexpr int C4 = K / 4;
        #pragma unroll
        for (int it = 0; it < 32 * C4 / 256; ++it) {
            int idx = it * 256 + t;
            int row = idx / C4, c4 = idx % C4;
            uint2 u = *(const uint2*)&((const ushort_t*)xin)[(size_t)(m0 + row) * K + c4 * 4];
            *(uint2*)&As[row][c4 * 4] = u;
        }
    }
    __syncthreads();

    f32x4 acc[5][2];
    f32x4 zero = {0.f, 0.f, 0.f, 0.f};
    #pragma unroll
    for (int m = 0; m < 5; ++m) { acc[m][0] = zero; acc[m][1] = zero; }

    #pragma unroll
    for (int ks = 0; ks < K / 32; ++ks) {
        short8 a0 = *(const short8*)&As[cl][ks * 32 + q4 * 8];
        short8 a1 = *(const short8*)&As[16 + cl][ks * 32 + q4 * 8];
        #pragma unroll
        for (int m = 0; m < 5; ++m) {
            acc[m][0] = __builtin_amdgcn_mfma_f32_16x16x32_bf16(a0, bfrag[m][ks], acc[m][0], 0, 0, 0);
            acc[m][1] = __builtin_amdgcn_mfma_f32_16x16x32_bf16(a1, bfrag[m][ks], acc[m][1], 0, 0, 0);
        }
    }

    #pragma unroll
    for (int rt = 0; rt < 2; ++rt) {
        #pragma unroll
        for (int r = 0; r < 4; ++r) {
            int row = m0 + rt * 16 + q4 * 4 + r;
            float qv = acc[0][rt][r] + bias[0];
            float gv = acc[1][rt][r] + bias[1];
            float kk = acc[2][rt][r] + bias[2];
            float vv = acc[3][rt][r] + bias[3];
            float sv = acc[4][rt][r] + bias[4];
            qgp[(size_t)row * 64 + col] = pack2(qv, gv);
            kvp[(size_t)row * 64 + col] = pack2(kk, vv);
            skp[(size_t)row * 64 + col] = (ushort_t)bf16rne(sv);
        }
    }
}

// ============================ CSR edge pass v12 ============================
// r17 structure; clamps removed (lanes>=rem hold 0 via ternary -> safe dummy
// loads of row 0); raw v_exp via EXP2. scale pre-multiplied by log2(e).
template<int C, int CHUNK, typename OT>
__global__ __launch_bounds__(256) void edge_csr(
    const int* __restrict__ rowptr, const int2* __restrict__ es,
    const float* __restrict__ ef, const float* __restrict__ We,
    const unsigned* __restrict__ qgp, const unsigned* __restrict__ kvp,
    const ushort_t* __restrict__ skp, OT* __restrict__ out,
    float scale, int do_relu)
{
    __shared__ float Wel[32 * 64];
    __shared__ float exl[4][64];
    int t = threadIdx.x;
    for (int i = t; i < 32 * 64; i += 256) Wel[i] = We[i];
    __syncthreads();

    int lane  = t & 63;
    int wslot = t >> 6;
    int col   = lane & 31;
    int hsel  = (C == 64) ? 0 : (lane >> 5);

    int wid = blockIdx.x * 4 + wslot;
    int nw  = gridDim.x * 4;

    for (int d0 = wid; d0 < N_NODES; d0 += nw) {
        int d = __builtin_amdgcn_readfirstlane(d0);
        int r0 = rowptr[d], r1 = rowptr[d + 1];
        unsigned uqg = __builtin_nontemporal_load(&qgp[(size_t)d * 64 + lane]);
        float qv = unpack_lo(uqg), gv = unpack_hi(uqg);
        float racc = 0.f, efacc = 0.f, rden = 0.f;

        for (int c0 = r0; c0 < r1; c0 += CHUNK) {
            int rem = min(CHUNK, r1 - c0);
            long long ll = (lane < rem)
                ? __builtin_nontemporal_load((const long long*)&es[c0 + lane]) : 0LL;
            int e_l = (int)ll;
            int s_l = (int)(ll >> 32);

            // prologue: edges 0,1 (indices beyond rem read lane value 0 -> row 0, safe)
            int eA = __builtin_amdgcn_readlane(e_l, 0);
            int sA = __builtin_amdgcn_readlane(s_l, 0);
            int eB = __builtin_amdgcn_readlane(e_l, 1);
            int sB = __builtin_amdgcn_readlane(s_l, 1);
            float    efA = __builtin_nontemporal_load(&ef[(size_t)eA * 32 + col]);
            unsigned uA  = kvp[(size_t)sA * 64 + lane];
            float    efB = __builtin_nontemporal_load(&ef[(size_t)eB * 32 + col]);
            unsigned uB  = kvp[(size_t)sB * 64 + lane];

            for (int i = 0; i < rem; i += 2) {
                int eN0 = __builtin_amdgcn_readlane(e_l, i + 2);
                int sN0 = __builtin_amdgcn_readlane(s_l, i + 2);
                int eN1 = __builtin_amdgcn_readlane(e_l, i + 3);
                int sN1 = __builtin_amdgcn_readlane(s_l, i + 3);
                float    efN0 = __builtin_nontemporal_load(&ef[(size_t)eN0 * 32 + col]);
                unsigned uN0  = kvp[(size_t)sN0 * 64 + lane];
                float    efN1 = __builtin_nontemporal_load(&ef[(size_t)eN1 * 32 + col]);
                unsigned uN1  = kvp[(size_t)sN1 * 64 + lane];

                {
                    float kk = unpack_lo(uA), vv = unpack_hi(uA);
                    float p = reduce32(fmaf(qv, kk, efA * gv));
                    if (C == 64) p += __shfl_xor(p, 32, 64);
                    float ex = EXP2(p * scale);
                    racc  = fmaf(vv,  ex, racc);
                    efacc = fmaf(efA, ex, efacc);
                    rden += ex;
                }
                if (i + 1 < rem) {
                    float kk = unpack_lo(uB), vv = unpack_hi(uB);
                    float p = reduce32(fmaf(qv, kk, efB * gv));
                    if (C == 64) p += __shfl_xor(p, 32, 64);
                    float ex = EXP2(p * scale);
                    racc  = fmaf(vv,  ex, racc);
                    efacc = fmaf(efB, ex, efacc);
                    rden += ex;
                }

                efA = efN0; uA = uN0;
                efB = efN1; uB = uN1;
            }
        }

        // finalize: (racc + efacc @ We) / rden + skip
        exl[wslot][lane] = efacc;
        float mv = 0.f;
        #pragma unroll 8
        for (int j = 0; j < 32; ++j)
            mv = fmaf(exl[wslot][hsel * 32 + j], Wel[j * 64 + lane], mv);
        float val = (racc + mv) / (rden + 1e-16f)
                  + bf2f(__builtin_nontemporal_load(&skp[(size_t)d * 64 + lane]));
        if (do_relu) val = fmaxf(val, 0.f);
        if constexpr (sizeof(OT) == 4)
            __builtin_nontemporal_store(val, &out[(size_t)d * 64 + lane]);
        else
            out[(size_t)d * 64 + lane] = (OT)bf16rne(val);
    }
}

extern "C" void kernel_launch(void* const* d_in, const int* in_sizes, int n_in,
                              void* d_out, int out_size, void* d_ws, size_t ws_size,
                              hipStream_t stream) {
    const float* x   = (const float*)d_in[0];
    const int*   ei  = (const int*)d_in[1];
    const float* ef  = (const float*)d_in[2];
    const float* Wq1 = (const float*)d_in[3];  const float* bq1 = (const float*)d_in[4];
    const float* Wk1 = (const float*)d_in[5];  const float* bk1 = (const float*)d_in[6];
    const float* Wv1 = (const float*)d_in[7];  const float* bv1 = (const float*)d_in[8];
    const float* We1 = (const float*)d_in[9];
    const float* Ws1 = (const float*)d_in[10]; const float* bs1 = (const float*)d_in[11];
    const float* Wq2 = (const float*)d_in[12]; const float* bq2 = (const float*)d_in[13];
    const float* Wk2 = (const float*)d_in[14]; const float* bk2 = (const float*)d_in[15];
    const float* Wv2 = (const float*)d_in[16]; const float* bv2 = (const float*)d_in[17];
    const float* We2 = (const float*)d_in[18];
    const float* Ws2 = (const float*)d_in[19]; const float* bs2 = (const float*)d_in[20];
    float* out = (float*)d_out;

    const int N = N_NODES, E = N_EDGES;
    size_t NF = (size_t)N * 64;
    unsigned* qgp  = (unsigned*)d_ws;              // N*64 u32 (bf16 q|g)
    unsigned* kvp  = qgp + NF;                     // N*64 u32 (bf16 k|v)
    ushort_t* skp  = (ushort_t*)(kvp + NF);        // N*64 bf16 skip
    ushort_t* h1b  = skp + NF;                     // N*64 bf16 (layer-1 output)
    ushort_t* Wtb1 = h1b + NF;                     // 320*128 bf16
    float*    bcat1= (float*)(Wtb1 + 320 * 128);   // 320
    ushort_t* Wtb2 = (ushort_t*)(bcat1 + 320);     // 320*64 bf16
    float*    bcat2= (float*)(Wtb2 + 320 * 64);    // 320
    int* cnt    = (int*)(bcat2 + 320);             // N
    int* excl   = cnt + N;                         // N
    int* bsum   = excl + N;                        // 128
    int* cursor = bsum + 128;                      // N
    int* rowptr = cursor + N;                      // N+1 (+1 pad)
    int2* es    = (int2*)(rowptr + N + 2);         // E (edge id | src), 8B aligned

    const int* src = ei;
    const int* dst = ei + E;

    dim3 b256(256);
    int gN1   = (N + 1 + 255) / 256;
    int gE    = (E + 255) / 256;
    int gGemm = N / 32;                            // 3125 exactly
    int gEdge = 2048;
    int nScanB = (N + 1023) / 1024;

    // scale premultiplied by log2(e) for exp2
    const float s1 = 0.17677669529663687f * 1.4426950408889634f;
    const float s2 = 0.125f * 1.4426950408889634f;

    // ---------------- weight prep + cnt zeroing (one launch) ----------------
    hipLaunchKernelGGL(prep_weights, dim3(96), b256, 0, stream,
                       Wq1, Wk1, Wv1, Ws1, bq1, bk1, bv1, bs1, We1,
                       Wq2, Wk2, Wv2, Ws2, bq2, bk2, bv2, bs2, We2,
                       Wtb1, bcat1, Wtb2, bcat2, cnt);

    // ---------------- CSR build (shared by both layers) ----------------
    hipLaunchKernelGGL(hist_kernel, dim3(gE), b256, 0, stream, dst, cnt);
    hipLaunchKernelGGL(scan1, dim3(nScanB), b256, 0, stream, cnt, excl, bsum, N);
    hipLaunchKernelGGL(scan2, dim3(1), dim3(128), 0, stream, bsum, nScanB);
    hipLaunchKernelGGL(scan3, dim3(gN1), b256, 0, stream, excl, bsum, rowptr, cursor, N);
    hipLaunchKernelGGL(scatter_kernel, dim3(gE), b256, 0, stream, dst, src, cursor, es);

    // ---------------- layer 1: H=2, C=32, K=128 ----------------
    hipLaunchKernelGGL((gemm_mfma<128, float>), dim3(gGemm), b256, 0, stream,
                       x, Wtb1, bcat1, qgp, kvp, skp);
    hipLaunchKernelGGL((edge_csr<32, 16, ushort_t>), dim3(gEdge), b256, 0, stream,
                       rowptr, es, ef, We1, qgp, kvp, skp, h1b, s1, 1);

    // ---------------- layer 2: H=1, C=64, K=64 ----------------
    hipLaunchKernelGGL((gemm_mfma<64, ushort_t>), dim3(gGemm), b256, 0, stream,
                       h1b, Wtb2, bcat2, qgp, kvp, skp);
    hipLaunchKernelGGL((edge_csr<64, 16, float>), dim3(gEdge), b256, 0, stream,
                       rowptr, es, ef, We2, qgp, kvp, skp, out, s2, 0);
}